// Round 7
// baseline (2062.930 us; speedup 1.0000x reference)
//
#include <hip/hip_runtime.h>
#include <math.h>

#define NN   262144      // nodes
#define CIN  200         // input channels
#define EE   2097152     // edges
#define NB   (2*NN)      // flat count/ptr sections: [row | col]
#define NBK  1024        // scatter buckets (512 flat-nodes each)
#define BSH  9           // log2(nodes per bucket)
#define EPSV 1e-5f

typedef __bf16 bf16x8 __attribute__((ext_vector_type(8)));
typedef float  f32x4  __attribute__((ext_vector_type(4)));

__device__ __forceinline__ unsigned short f2bf(float f) {
    unsigned int u = __float_as_uint(f);
    unsigned int r = (u + 0x7fffu + ((u >> 16) & 1u)) >> 16;
    return (unsigned short)r;
}
__device__ __forceinline__ float bf2f(unsigned short u) {
    return __uint_as_float(((unsigned int)u) << 16);
}

// ---------------- stem GEMM: t = x @ W + b   ([N,200] @ [200,64]) --------------
__global__ __launch_bounds__(256) void stem_gemm(
    const float* __restrict__ x, const float* __restrict__ W,
    const float* __restrict__ bias, float* __restrict__ t)
{
    __shared__ float sA[40][64];
    __shared__ float sB[40][64];
    const int tid = threadIdx.x;
    const int rid = tid >> 4;
    const int cid = tid & 15;
    const int row0 = blockIdx.x * 64;

    float acc[4][4];
#pragma unroll
    for (int i = 0; i < 4; ++i)
#pragma unroll
        for (int j = 0; j < 4; ++j) acc[i][j] = 0.f;

    for (int k0 = 0; k0 < CIN; k0 += 40) {
        __syncthreads();
        for (int idx = tid; idx < 64 * 40; idx += 256) {
            int r = idx / 40, kk = idx % 40;
            sA[kk][r] = x[(size_t)(row0 + r) * CIN + k0 + kk];
        }
        for (int idx = tid; idx < 40 * 64; idx += 256) {
            int kk = idx >> 6, c = idx & 63;
            sB[kk][c] = W[(k0 + kk) * 64 + c];
        }
        __syncthreads();
#pragma unroll
        for (int kk = 0; kk < 40; ++kk) {
            const float4 a4 = *(const float4*)&sA[kk][rid * 4];
            const float4 b4 = *(const float4*)&sB[kk][cid * 4];
            acc[0][0] = fmaf(a4.x, b4.x, acc[0][0]);
            acc[0][1] = fmaf(a4.x, b4.y, acc[0][1]);
            acc[0][2] = fmaf(a4.x, b4.z, acc[0][2]);
            acc[0][3] = fmaf(a4.x, b4.w, acc[0][3]);
            acc[1][0] = fmaf(a4.y, b4.x, acc[1][0]);
            acc[1][1] = fmaf(a4.y, b4.y, acc[1][1]);
            acc[1][2] = fmaf(a4.y, b4.z, acc[1][2]);
            acc[1][3] = fmaf(a4.y, b4.w, acc[1][3]);
            acc[2][0] = fmaf(a4.z, b4.x, acc[2][0]);
            acc[2][1] = fmaf(a4.z, b4.y, acc[2][1]);
            acc[2][2] = fmaf(a4.z, b4.z, acc[2][2]);
            acc[2][3] = fmaf(a4.z, b4.w, acc[2][3]);
            acc[3][0] = fmaf(a4.w, b4.x, acc[3][0]);
            acc[3][1] = fmaf(a4.w, b4.y, acc[3][1]);
            acc[3][2] = fmaf(a4.w, b4.z, acc[3][2]);
            acc[3][3] = fmaf(a4.w, b4.w, acc[3][3]);
        }
    }
    const float4 bb = *(const float4*)&bias[cid * 4];
#pragma unroll
    for (int i = 0; i < 4; ++i) {
        float4 o;
        o.x = acc[i][0] + bb.x;
        o.y = acc[i][1] + bb.y;
        o.z = acc[i][2] + bb.z;
        o.w = acc[i][3] + bb.w;
        *(float4*)&t[(size_t)(row0 + rid * 4 + i) * 64 + cid * 4] = o;
    }
}

// ---------------- per-channel batch stats (stem only) --------------------------
__global__ __launch_bounds__(256) void stats_kernel(
    const float* __restrict__ src, float* __restrict__ stats)
{
    const int c = threadIdx.x & 63;
    const int rg = threadIdx.x >> 6;
    float s = 0.f, s2 = 0.f;
    for (int row = blockIdx.x * 4 + rg; row < NN; row += gridDim.x * 4) {
        float v = src[(size_t)row * 64 + c];
        s += v;
        s2 += v * v;
    }
    __shared__ float ls[4][64], ls2[4][64];
    ls[rg][c] = s;
    ls2[rg][c] = s2;
    __syncthreads();
    if (threadIdx.x < 64) {
        atomicAdd(&stats[c],      ls[0][c] + ls[1][c] + ls[2][c] + ls[3][c]);
        atomicAdd(&stats[64 + c], ls2[0][c] + ls2[1][c] + ls2[2][c] + ls2[3][c]);
    }
}

// fold BN into per-channel affine:  bn(v) = v*a + c
__global__ void finalize_bn(const float* __restrict__ stats,
                            const float* __restrict__ g, const float* __restrict__ b,
                            float* __restrict__ ac)
{
    int c = threadIdx.x;
    float mean = stats[c] * (1.f / NN);
    float var  = stats[64 + c] * (1.f / NN) - mean * mean;
    float rstd = rsqrtf(var + EPSV);
    float a = g[c] * rstd;
    ac[c]      = a;
    ac[64 + c] = b[c] - mean * a;
}

// ---- ln: xn = LN(leaky?(affine(u)));  writes fp32 xn + bf16 xnb ---------------
template <int RELU>
__global__ __launch_bounds__(256) void ln_kernel(
    const float* __restrict__ u, const float* __restrict__ ac,
    const float* __restrict__ lng, const float* __restrict__ lnb,
    float* __restrict__ xn, unsigned short* __restrict__ xnb)
{
    const int lane = threadIdx.x & 63;
    const int wid  = (blockIdx.x * 256 + threadIdx.x) >> 6;
    const int nw   = (gridDim.x * 256) >> 6;
    const float a  = ac[lane],  c0 = ac[64 + lane];
    const float g  = lng[lane], bl = lnb[lane];

    for (int row = wid; row < NN; row += nw) {
        float v = u[(size_t)row * 64 + lane];
        v = v * a + c0;
        if (RELU) v = (v > 0.f) ? v : 0.01f * v;
        float s = v;
#pragma unroll
        for (int off = 32; off > 0; off >>= 1) s += __shfl_xor(s, off);
        float mean = s * (1.f / 64.f);
        float d = v - mean;
        float s2 = d * d;
#pragma unroll
        for (int off = 32; off > 0; off >>= 1) s2 += __shfl_xor(s2, off);
        float rstd = rsqrtf(s2 * (1.f / 64.f) + EPSV);
        float o = d * rstd * g + bl;
        xn[(size_t)row * 64 + lane] = o;
        xnb[(size_t)row * 64 + lane] = f2bf(o);
    }
}

// ================= CSR build (graph identical for both layers) ==================
__global__ __launch_bounds__(256) void hist_kernel(
    const int* __restrict__ rowsrc, const int* __restrict__ colsrc,
    int* __restrict__ cnt)
{
    for (int i = blockIdx.x * 256 + threadIdx.x; i < EE; i += gridDim.x * 256) {
        atomicAdd(&cnt[rowsrc[i]], 1);
        atomicAdd(&cnt[NN + colsrc[i]], 1);
    }
}

__global__ __launch_bounds__(256) void scan1_kernel(
    const int* __restrict__ cnt, int* __restrict__ bsum)
{
    const int t = threadIdx.x;
    const int base = blockIdx.x * 1024 + t * 4;
    int s = cnt[base] + cnt[base + 1] + cnt[base + 2] + cnt[base + 3];
    __shared__ int sm[256];
    sm[t] = s;
    __syncthreads();
    for (int off = 1; off < 256; off <<= 1) {
        int v = (t >= off) ? sm[t - off] : 0;
        __syncthreads();
        sm[t] += v;
        __syncthreads();
    }
    if (t == 255) bsum[blockIdx.x] = sm[255];
}

__global__ __launch_bounds__(512) void scan2_kernel(
    const int* __restrict__ bsum, int* __restrict__ bpre, int* __restrict__ ptr)
{
    const int t = threadIdx.x;
    __shared__ int sm[512];
    int orig = bsum[t];
    sm[t] = orig;
    __syncthreads();
    for (int off = 1; off < 512; off <<= 1) {
        int v = (t >= off) ? sm[t - off] : 0;
        __syncthreads();
        sm[t] += v;
        __syncthreads();
    }
    bpre[t] = sm[t] - orig;
    if (t == 0) ptr[NB] = 2 * EE;
}

__global__ __launch_bounds__(256) void scan3_kernel(
    const int* __restrict__ cnt, const int* __restrict__ bpre,
    int* __restrict__ ptr, int* __restrict__ cursor)
{
    const int t = threadIdx.x;
    const int base = blockIdx.x * 1024 + t * 4;
    int c0 = cnt[base], c1 = cnt[base + 1], c2 = cnt[base + 2], c3 = cnt[base + 3];
    int tsum = c0 + c1 + c2 + c3;
    __shared__ int sm[256];
    sm[t] = tsum;
    __syncthreads();
    for (int off = 1; off < 256; off <<= 1) {
        int v = (t >= off) ? sm[t - off] : 0;
        __syncthreads();
        sm[t] += v;
        __syncthreads();
    }
    int p = bpre[blockIdx.x] + sm[t] - tsum;
    ptr[base] = p;     cursor[base] = p;     p += c0;
    ptr[base + 1] = p; cursor[base + 1] = p; p += c1;
    ptr[base + 2] = p; cursor[base + 2] = p; p += c2;
    ptr[base + 3] = p; cursor[base + 3] = p;
}

// ---- bucket histogram (LDS-aggregated) ----------------------------------------
__global__ __launch_bounds__(256) void bhist_kernel(
    const int* __restrict__ rowsrc, const int* __restrict__ colsrc,
    int* __restrict__ bcnt)
{
    __shared__ int h[NBK];
    for (int i = threadIdx.x; i < NBK; i += 256) h[i] = 0;
    __syncthreads();
    for (int i = blockIdx.x * 256 + threadIdx.x; i < EE; i += gridDim.x * 256) {
        atomicAdd(&h[rowsrc[i] >> BSH], 1);
        atomicAdd(&h[512 + (colsrc[i] >> BSH)], 1);
    }
    __syncthreads();
    for (int i = threadIdx.x; i < NBK; i += 256) {
        int v = h[i];
        if (v) atomicAdd(&bcnt[i], v);
    }
}

// ---- bucket scan: exclusive scan of 1024 counts -> bbase, bcur ----------------
__global__ __launch_bounds__(256) void bscan_kernel(
    const int* __restrict__ bcnt, int* __restrict__ bbase, int* __restrict__ bcur)
{
    const int t = threadIdx.x;
    const int base = t * 4;
    int c0 = bcnt[base], c1 = bcnt[base + 1], c2 = bcnt[base + 2], c3 = bcnt[base + 3];
    int tsum = c0 + c1 + c2 + c3;
    __shared__ int sm[256];
    sm[t] = tsum;
    __syncthreads();
    for (int off = 1; off < 256; off <<= 1) {
        int v = (t >= off) ? sm[t - off] : 0;
        __syncthreads();
        sm[t] += v;
        __syncthreads();
    }
    int p = sm[t] - tsum;
    bbase[base] = p;     bcur[base] = p;     p += c0;
    bbase[base + 1] = p; bcur[base + 1] = p; p += c1;
    bbase[base + 2] = p; bcur[base + 2] = p; p += c2;
    bbase[base + 3] = p; bcur[base + 3] = p;
    if (t == 255) bbase[NBK] = 2 * EE;
}

// ---- bucket fill: append (src,dst,att) per bucket (sequential writes) ---------
__global__ __launch_bounds__(256) void bfill_kernel(
    const int* __restrict__ rowsrc, const int* __restrict__ rowdst,
    const float* __restrict__ ratt,
    const int* __restrict__ colsrc, const int* __restrict__ coldst,
    const float* __restrict__ catt,
    int* __restrict__ bcur,
    int* __restrict__ bsrc, int* __restrict__ bdst, float* __restrict__ batt)
{
    for (int i = blockIdx.x * 256 + threadIdx.x; i < EE; i += gridDim.x * 256) {
        int s = rowsrc[i];
        int p = atomicAdd(&bcur[s >> BSH], 1);
        bsrc[p] = s;
        bdst[p] = rowdst[i];
        batt[p] = ratt[i];
        int s2 = colsrc[i];
        int q = atomicAdd(&bcur[512 + (s2 >> BSH)], 1);
        bsrc[q] = NN + s2;
        bdst[q] = coldst[i];
        batt[q] = catt[i];
    }
}

// ---- bucket flush: per-bucket sequential read, scatter into 32KB CSR window ---
__global__ __launch_bounds__(256) void bflush_kernel(
    const int* __restrict__ bbase,
    const int* __restrict__ bsrc, const int* __restrict__ bdst,
    const float* __restrict__ batt,
    int* __restrict__ cursor, int2* __restrict__ edges)
{
    const int b = blockIdx.x;
    const int lo = bbase[b], hi = bbase[b + 1];
    for (int i = lo + threadIdx.x; i < hi; i += 256) {
        int s = bsrc[i];
        int q = atomicAdd(&cursor[s], 1);
        edges[q] = make_int2(bdst[i], __float_as_int(batt[i]));
    }
}

// ---- pure gather: rx[n] = Σ att·xnb[dst] (row), cx[n] = Σ att·xnb[dst] (col) --
__global__ __launch_bounds__(256) void gather_kernel(
    const unsigned short* __restrict__ xnb,
    const int* __restrict__ ptr, const int2* __restrict__ edges,
    unsigned short* __restrict__ rxb, unsigned short* __restrict__ cxb,
    float2* __restrict__ attsum)
{
    const int lane = threadIdx.x & 63;
    const int wid  = (blockIdx.x * 256 + threadIdx.x) >> 6;
    const int nw   = (gridDim.x * 256) >> 6;

    for (int n = wid; n < NN; n += nw) {
        float rx = 0.f, ras = 0.f, cx = 0.f, cas = 0.f;

        int b0 = ptr[n], e0 = ptr[n + 1];
        int i = b0;
        for (; i + 8 <= e0; i += 8) {
            int2 p0 = edges[i],     p1 = edges[i + 1];
            int2 p2 = edges[i + 2], p3 = edges[i + 3];
            int2 p4 = edges[i + 4], p5 = edges[i + 5];
            int2 p6 = edges[i + 6], p7 = edges[i + 7];
            float v0 = bf2f(xnb[(size_t)p0.x * 64 + lane]);
            float v1 = bf2f(xnb[(size_t)p1.x * 64 + lane]);
            float v2 = bf2f(xnb[(size_t)p2.x * 64 + lane]);
            float v3 = bf2f(xnb[(size_t)p3.x * 64 + lane]);
            float v4 = bf2f(xnb[(size_t)p4.x * 64 + lane]);
            float v5 = bf2f(xnb[(size_t)p5.x * 64 + lane]);
            float v6 = bf2f(xnb[(size_t)p6.x * 64 + lane]);
            float v7 = bf2f(xnb[(size_t)p7.x * 64 + lane]);
            float a0 = __int_as_float(p0.y), a1 = __int_as_float(p1.y);
            float a2 = __int_as_float(p2.y), a3 = __int_as_float(p3.y);
            float a4 = __int_as_float(p4.y), a5 = __int_as_float(p5.y);
            float a6 = __int_as_float(p6.y), a7 = __int_as_float(p7.y);
            rx = fmaf(v0, a0, rx); ras += a0;
            rx = fmaf(v1, a1, rx); ras += a1;
            rx = fmaf(v2, a2, rx); ras += a2;
            rx = fmaf(v3, a3, rx); ras += a3;
            rx = fmaf(v4, a4, rx); ras += a4;
            rx = fmaf(v5, a5, rx); ras += a5;
            rx = fmaf(v6, a6, rx); ras += a6;
            rx = fmaf(v7, a7, rx); ras += a7;
        }
        for (; i < e0; ++i) {
            int2 p = edges[i];
            float a = __int_as_float(p.y);
            rx = fmaf(bf2f(xnb[(size_t)p.x * 64 + lane]), a, rx);
            ras += a;
        }

        int b1 = ptr[NN + n], e1 = ptr[NN + n + 1];
        i = b1;
        for (; i + 8 <= e1; i += 8) {
            int2 p0 = edges[i],     p1 = edges[i + 1];
            int2 p2 = edges[i + 2], p3 = edges[i + 3];
            int2 p4 = edges[i + 4], p5 = edges[i + 5];
            int2 p6 = edges[i + 6], p7 = edges[i + 7];
            float v0 = bf2f(xnb[(size_t)p0.x * 64 + lane]);
            float v1 = bf2f(xnb[(size_t)p1.x * 64 + lane]);
            float v2 = bf2f(xnb[(size_t)p2.x * 64 + lane]);
            float v3 = bf2f(xnb[(size_t)p3.x * 64 + lane]);
            float v4 = bf2f(xnb[(size_t)p4.x * 64 + lane]);
            float v5 = bf2f(xnb[(size_t)p5.x * 64 + lane]);
            float v6 = bf2f(xnb[(size_t)p6.x * 64 + lane]);
            float v7 = bf2f(xnb[(size_t)p7.x * 64 + lane]);
            float a0 = __int_as_float(p0.y), a1 = __int_as_float(p1.y);
            float a2 = __int_as_float(p2.y), a3 = __int_as_float(p3.y);
            float a4 = __int_as_float(p4.y), a5 = __int_as_float(p5.y);
            float a6 = __int_as_float(p6.y), a7 = __int_as_float(p7.y);
            cx = fmaf(v0, a0, cx); cas += a0;
            cx = fmaf(v1, a1, cx); cas += a1;
            cx = fmaf(v2, a2, cx); cas += a2;
            cx = fmaf(v3, a3, cx); cas += a3;
            cx = fmaf(v4, a4, cx); cas += a4;
            cx = fmaf(v5, a5, cx); cas += a5;
            cx = fmaf(v6, a6, cx); cas += a6;
            cx = fmaf(v7, a7, cx); cas += a7;
        }
        for (; i < e1; ++i) {
            int2 p = edges[i];
            float a = __int_as_float(p.y);
            cx = fmaf(bf2f(xnb[(size_t)p.x * 64 + lane]), a, cx);
            cas += a;
        }

        rxb[(size_t)n * 64 + lane] = f2bf(rx);
        cxb[(size_t)n * 64 + lane] = f2bf(cx);
        if (lane == 0) attsum[n] = make_float2(ras, cas);
    }
}

// ---- weight pre-swizzle into MFMA B-fragment layout (bf16) --------------------
__global__ __launch_bounds__(256) void w_convert(
    const float* __restrict__ Wrv, const float* __restrict__ Wcv,
    unsigned short* __restrict__ wbuf)
{
    int idx = blockIdx.x * 256 + threadIdx.x;   // 0..16383
    int e    = idx & 7;
    int lane = (idx >> 3) & 63;
    int t    = (idx >> 9) & 3;
    int kb   = (idx >> 11) & 1;
    int m    = (idx >> 12) & 1;
    int L    = (idx >> 13) & 1;
    const float* W = (m ? Wcv : Wrv) + L * 4096;
    float w = W[(kb * 32 + ((lane >> 4) & 3) * 8 + e) * 64 + t * 16 + (lane & 15)];
    wbuf[idx] = f2bf(w);
}

// ---- MFMA epilogue: out = xn + rx@Wr + cx@Wc + ras·br + cas·bc; fused stats ---
__global__ __launch_bounds__(256) void gemv_mfma(
    const unsigned short* __restrict__ rxb, const unsigned short* __restrict__ cxb,
    const float* __restrict__ xn, const float2* __restrict__ attsum,
    const unsigned short* __restrict__ wb16,
    const float* __restrict__ br, const float* __restrict__ bc,
    float* __restrict__ out, float* __restrict__ stats)
{
    const int lane = threadIdx.x & 63;
    const int wloc = threadIdx.x >> 6;
    const int wid  = (blockIdx.x * 256 + threadIdx.x) >> 6;
    const int nw   = (gridDim.x * 256) >> 6;
    const int lo   = lane & 15;
    const int hi   = lane >> 4;

    const bf16x8* wb = (const bf16x8*)wb16;
    bf16x8 bfr[2][2][4];
#pragma unroll
    for (int m = 0; m < 2; ++m)
#pragma unroll
        for (int kb = 0; kb < 2; ++kb)
#pragma unroll
            for (int t = 0; t < 4; ++t)
                bfr[m][kb][t] = wb[((m * 2 + kb) * 4 + t) * 64 + lane];

    float brv4[4], bcv4[4];
#pragma unroll
    for (int t = 0; t < 4; ++t) {
        brv4[t] = br[t * 16 + lo];
        bcv4[t] = bc[t * 16 + lo];
    }

    float ss[4] = {0.f, 0.f, 0.f, 0.f}, ss2[4] = {0.f, 0.f, 0.f, 0.f};
    const bf16x8* ra = (const bf16x8*)rxb;
    const bf16x8* ca = (const bf16x8*)cxb;

    for (int tile = wid; tile < NN / 16; tile += nw) {
        const int n0 = tile * 16;
        const int arow = n0 + lo;
        bf16x8 a0 = ra[arow * 8 + hi];
        bf16x8 a1 = ra[arow * 8 + 4 + hi];
        bf16x8 c0 = ca[arow * 8 + hi];
        bf16x8 c1 = ca[arow * 8 + 4 + hi];
        float2 an[4];
#pragma unroll
        for (int r = 0; r < 4; ++r) an[r] = attsum[n0 + hi * 4 + r];

#pragma unroll
        for (int t = 0; t < 4; ++t) {
            f32x4 acc = {0.f, 0.f, 0.f, 0.f};
            acc = __builtin_amdgcn_mfma_f32_16x16x32_bf16(a0, bfr[0][0][t], acc, 0, 0, 0);
            acc = __builtin_amdgcn_mfma_f32_16x16x32_bf16(a1, bfr[0][1][t], acc, 0, 0, 0);
            acc = __builtin_amdgcn_mfma_f32_16x16x32_bf16(c0, bfr[1][0][t], acc, 0, 0, 0);
            acc = __builtin_amdgcn_mfma_f32_16x16x32_bf16(c1, bfr[1][1][t], acc, 0, 0, 0);
            const int col = t * 16 + lo;
#pragma unroll
            for (int r = 0; r < 4; ++r) {
                const int n = n0 + hi * 4 + r;
                float v = acc[r] + xn[(size_t)n * 64 + col]
                        + an[r].x * brv4[t] + an[r].y * bcv4[t];
                out[(size_t)n * 64 + col] = v;
                ss[t] += v;
                ss2[t] += v * v;
            }
        }
    }

    // stats reduce: lanes sharing the same (lane&15) hold the same channels
#pragma unroll
    for (int t = 0; t < 4; ++t) {
        ss[t]  += __shfl_xor(ss[t], 16);  ss[t]  += __shfl_xor(ss[t], 32);
        ss2[t] += __shfl_xor(ss2[t], 16); ss2[t] += __shfl_xor(ss2[t], 32);
    }
    __shared__ float ls[4][64], ls2[4][64];
    if (lo == lane) {   // lanes 0..15
#pragma unroll
        for (int t = 0; t < 4; ++t) {
            ls[wloc][t * 16 + lane]  = ss[t];
            ls2[wloc][t * 16 + lane] = ss2[t];
        }
    }
    __syncthreads();
    if (threadIdx.x < 64) {
        int ch = threadIdx.x;
        atomicAdd(&stats[ch],      ls[0][ch] + ls[1][ch] + ls[2][ch] + ls[3][ch]);
        atomicAdd(&stats[64 + ch], ls2[0][ch] + ls2[1][ch] + ls2[2][ch] + ls2[3][ch]);
    }
}

// ------ fused output: affine+leaky -> logits = h@smW + b -> softmax ------------
__global__ __launch_bounds__(256) void out_kernel(
    const float* __restrict__ agg, const float* __restrict__ ac,
    const float* __restrict__ smW, const float* __restrict__ smb,
    float* __restrict__ out)
{
    __shared__ float sW[64 * 16];
    for (int i = threadIdx.x; i < 64 * 16; i += 256) sW[i] = smW[i];
    __syncthreads();
    const int j = threadIdx.x & 15;
    const int rloc = threadIdx.x >> 4;
    const float bj = smb[j];
    for (int row = blockIdx.x * 16 + rloc; row < NN; row += gridDim.x * 16) {
        float acc = bj;
#pragma unroll
        for (int k = 0; k < 64; ++k) {
            float v = agg[(size_t)row * 64 + k];
            v = v * ac[k] + ac[64 + k];
            v = (v > 0.f) ? v : 0.01f * v;
            acc = fmaf(v, sW[k * 16 + j], acc);
        }
        float m = acc;
#pragma unroll
        for (int off = 8; off > 0; off >>= 1) m = fmaxf(m, __shfl_xor(m, off));
        float e = expf(acc - m);
        float ssum = e;
#pragma unroll
        for (int off = 8; off > 0; off >>= 1) ssum += __shfl_xor(ssum, off);
        out[(size_t)row * 16 + j] = e / ssum;
    }
}

// ------------------------------------------------------------------------------
extern "C" void kernel_launch(void* const* d_in, const int* in_sizes, int n_in,
                              void* d_out, int out_size, void* d_ws, size_t ws_size,
                              hipStream_t stream)
{
    const float* x        = (const float*)d_in[0];
    const float* row_att  = (const float*)d_in[1];
    const float* col_att  = (const float*)d_in[2];
    const float* prelin_W = (const float*)d_in[3];
    const float* prelin_b = (const float*)d_in[4];
    const float* bn0_g    = (const float*)d_in[5];
    const float* bn0_b    = (const float*)d_in[6];
    const float* ln_g     = (const float*)d_in[7];
    const float* ln_b     = (const float*)d_in[8];
    const float* Wrv      = (const float*)d_in[9];
    const float* brv      = (const float*)d_in[10];
    const float* Wcv      = (const float*)d_in[11];
    const float* bcv      = (const float*)d_in[12];
    const float* bn_g     = (const float*)d_in[13];
    const float* bn_b     = (const float*)d_in[14];
    const float* sm_W     = (const float*)d_in[15];
    const float* sm_b     = (const float*)d_in[16];
    const int*   rowsrc   = (const int*)d_in[17];
    const int*   rowdst   = (const int*)d_in[18];
    const int*   colsrc   = (const int*)d_in[19];
    const int*   coldst   = (const int*)d_in[20];
    float* out = (float*)d_out;

    // ---- workspace layout (~277 MB) ----
    const size_t NH = (size_t)NN * 64;
    float* A  = (float*)d_ws;                    // stem out / layer out
    float* xn = A + NH;                          // fp32 LN output (residual)

    char* extra = (char*)(xn + NH);
    unsigned short* xnb = (unsigned short*)extra; extra += NH * sizeof(short);
    unsigned short* rxb = (unsigned short*)extra; extra += NH * sizeof(short);
    unsigned short* cxb = (unsigned short*)extra; extra += NH * sizeof(short);
    float2* attsum = (float2*)extra;              extra += (size_t)NN * sizeof(float2);
    float* stats  = (float*)extra;                extra += 3 * 128 * sizeof(float);
    float* ac     = (float*)extra;                extra += 3 * 128 * sizeof(float);
    unsigned short* wbuf = (unsigned short*)extra; extra += 16384 * sizeof(short);
    int*   bsum   = (int*)extra;                  extra += 512 * sizeof(int);
    int*   bpre   = (int*)extra;                  extra += 512 * sizeof(int);
    int*   ptr    = (int*)extra;                  extra += (NB + 1) * sizeof(int);
    int*   counts = (int*)extra;                  extra += NB * sizeof(int);
    int*   cursor = (int*)extra;                  extra += NB * sizeof(int);
    int*   bcnt   = (int*)extra;                  extra += NBK * sizeof(int);
    int*   bbase  = (int*)extra;                  extra += (NBK + 1) * sizeof(int);
    int*   bcur   = (int*)extra;                  extra += NBK * sizeof(int);
    int2*  edges  = (int2*)extra;                 extra += 2 * (size_t)EE * sizeof(int2);

    // bucket staging arrays alias rxb/cxb (dead until first gather, which runs
    // after the CSR build completes)
    int*   bsrc = (int*)rxb;                      // 16.8 MB
    int*   bdst = bsrc + 2 * EE;                  // 16.8 MB (fills rest of rxb)
    float* batt = (float*)cxb;                    // 16.8 MB (first half of cxb)

    hipMemsetAsync(stats, 0, 3 * 128 * sizeof(float), stream);
    hipMemsetAsync(counts, 0, NB * sizeof(int), stream);
    hipMemsetAsync(bcnt, 0, NBK * sizeof(int), stream);

    // ---- CSR build (used by both layers) ----
    hist_kernel<<<2048, 256, 0, stream>>>(rowsrc, colsrc, counts);
    scan1_kernel<<<512, 256, 0, stream>>>(counts, bsum);
    scan2_kernel<<<1, 512, 0, stream>>>(bsum, bpre, ptr);
    scan3_kernel<<<512, 256, 0, stream>>>(counts, bpre, ptr, cursor);
    bhist_kernel<<<512, 256, 0, stream>>>(rowsrc, colsrc, bcnt);
    bscan_kernel<<<1, 256, 0, stream>>>(bcnt, bbase, bcur);
    bfill_kernel<<<2048, 256, 0, stream>>>(rowsrc, rowdst, row_att,
                                           colsrc, coldst, col_att,
                                           bcur, bsrc, bdst, batt);
    bflush_kernel<<<NBK, 256, 0, stream>>>(bbase, bsrc, bdst, batt,
                                           cursor, edges);
    w_convert<<<64, 256, 0, stream>>>(Wrv, Wcv, wbuf);

    // ---- stem ----
    stem_gemm<<<NN / 64, 256, 0, stream>>>(x, prelin_W, prelin_b, A);
    stats_kernel<<<1024, 256, 0, stream>>>(A, stats);
    finalize_bn<<<1, 64, 0, stream>>>(stats, bn0_g, bn0_b, ac);

    // ---- layer 0 ----
    ln_kernel<0><<<4096, 256, 0, stream>>>(A, ac, ln_g, ln_b, xn, xnb);
    gather_kernel<<<8192, 256, 0, stream>>>(xnb, ptr, edges, rxb, cxb, attsum);
    gemv_mfma<<<1024, 256, 0, stream>>>(rxb, cxb, xn, attsum, wbuf,
                                        brv, bcv, A, stats + 128);
    finalize_bn<<<1, 64, 0, stream>>>(stats + 128, bn_g, bn_b, ac + 128);

    // ---- layer 1 ----
    ln_kernel<1><<<4096, 256, 0, stream>>>(A, ac + 128, ln_g + 64, ln_b + 64, xn, xnb);
    gather_kernel<<<8192, 256, 0, stream>>>(xnb, ptr, edges, rxb, cxb, attsum);
    gemv_mfma<<<1024, 256, 0, stream>>>(rxb, cxb, xn, attsum, wbuf + 8192,
                                        brv + 64, bcv + 64, A, stats + 256);
    finalize_bn<<<1, 64, 0, stream>>>(stats + 256, bn_g + 64, bn_b + 64, ac + 256);

    // ---- output head ----
    out_kernel<<<2048, 256, 0, stream>>>(A, ac + 256, sm_W, sm_b, out);
}

// Round 8
// 1371.883 us; speedup vs baseline: 1.5037x; 1.5037x over previous
//
#include <hip/hip_runtime.h>
#include <math.h>

#define NN   262144      // nodes
#define CIN  200         // input channels
#define EE   2097152     // edges
#define NB   (2*NN)      // flat count/ptr sections: [row | col]
#define EPSV 1e-5f

typedef __bf16 bf16x8 __attribute__((ext_vector_type(8)));
typedef float  f32x4  __attribute__((ext_vector_type(4)));

__device__ __forceinline__ unsigned short f2bf(float f) {
    unsigned int u = __float_as_uint(f);
    unsigned int r = (u + 0x7fffu + ((u >> 16) & 1u)) >> 16;
    return (unsigned short)r;
}
__device__ __forceinline__ float bf2f(unsigned short u) {
    return __uint_as_float(((unsigned int)u) << 16);
}

// ---------------- stem GEMM: t = x @ W + b   ([N,200] @ [200,64]) --------------
__global__ __launch_bounds__(256) void stem_gemm(
    const float* __restrict__ x, const float* __restrict__ W,
    const float* __restrict__ bias, float* __restrict__ t)
{
    __shared__ float sA[40][64];
    __shared__ float sB[40][64];
    const int tid = threadIdx.x;
    const int rid = tid >> 4;
    const int cid = tid & 15;
    const int row0 = blockIdx.x * 64;

    float acc[4][4];
#pragma unroll
    for (int i = 0; i < 4; ++i)
#pragma unroll
        for (int j = 0; j < 4; ++j) acc[i][j] = 0.f;

    for (int k0 = 0; k0 < CIN; k0 += 40) {
        __syncthreads();
        for (int idx = tid; idx < 64 * 40; idx += 256) {
            int r = idx / 40, kk = idx % 40;
            sA[kk][r] = x[(size_t)(row0 + r) * CIN + k0 + kk];
        }
        for (int idx = tid; idx < 40 * 64; idx += 256) {
            int kk = idx >> 6, c = idx & 63;
            sB[kk][c] = W[(k0 + kk) * 64 + c];
        }
        __syncthreads();
#pragma unroll
        for (int kk = 0; kk < 40; ++kk) {
            const float4 a4 = *(const float4*)&sA[kk][rid * 4];
            const float4 b4 = *(const float4*)&sB[kk][cid * 4];
            acc[0][0] = fmaf(a4.x, b4.x, acc[0][0]);
            acc[0][1] = fmaf(a4.x, b4.y, acc[0][1]);
            acc[0][2] = fmaf(a4.x, b4.z, acc[0][2]);
            acc[0][3] = fmaf(a4.x, b4.w, acc[0][3]);
            acc[1][0] = fmaf(a4.y, b4.x, acc[1][0]);
            acc[1][1] = fmaf(a4.y, b4.y, acc[1][1]);
            acc[1][2] = fmaf(a4.y, b4.z, acc[1][2]);
            acc[1][3] = fmaf(a4.y, b4.w, acc[1][3]);
            acc[2][0] = fmaf(a4.z, b4.x, acc[2][0]);
            acc[2][1] = fmaf(a4.z, b4.y, acc[2][1]);
            acc[2][2] = fmaf(a4.z, b4.z, acc[2][2]);
            acc[2][3] = fmaf(a4.z, b4.w, acc[2][3]);
            acc[3][0] = fmaf(a4.w, b4.x, acc[3][0]);
            acc[3][1] = fmaf(a4.w, b4.y, acc[3][1]);
            acc[3][2] = fmaf(a4.w, b4.z, acc[3][2]);
            acc[3][3] = fmaf(a4.w, b4.w, acc[3][3]);
        }
    }
    const float4 bb = *(const float4*)&bias[cid * 4];
#pragma unroll
    for (int i = 0; i < 4; ++i) {
        float4 o;
        o.x = acc[i][0] + bb.x;
        o.y = acc[i][1] + bb.y;
        o.z = acc[i][2] + bb.z;
        o.w = acc[i][3] + bb.w;
        *(float4*)&t[(size_t)(row0 + rid * 4 + i) * 64 + cid * 4] = o;
    }
}

// ---------------- per-channel batch stats (stem only) --------------------------
__global__ __launch_bounds__(256) void stats_kernel(
    const float* __restrict__ src, float* __restrict__ stats)
{
    const int c = threadIdx.x & 63;
    const int rg = threadIdx.x >> 6;
    float s = 0.f, s2 = 0.f;
    for (int row = blockIdx.x * 4 + rg; row < NN; row += gridDim.x * 4) {
        float v = src[(size_t)row * 64 + c];
        s += v;
        s2 += v * v;
    }
    __shared__ float ls[4][64], ls2[4][64];
    ls[rg][c] = s;
    ls2[rg][c] = s2;
    __syncthreads();
    if (threadIdx.x < 64) {
        atomicAdd(&stats[c],      ls[0][c] + ls[1][c] + ls[2][c] + ls[3][c]);
        atomicAdd(&stats[64 + c], ls2[0][c] + ls2[1][c] + ls2[2][c] + ls2[3][c]);
    }
}

// fold BN into per-channel affine:  bn(v) = v*a + c
__global__ void finalize_bn(const float* __restrict__ stats,
                            const float* __restrict__ g, const float* __restrict__ b,
                            float* __restrict__ ac)
{
    int c = threadIdx.x;
    float mean = stats[c] * (1.f / NN);
    float var  = stats[64 + c] * (1.f / NN) - mean * mean;
    float rstd = rsqrtf(var + EPSV);
    float a = g[c] * rstd;
    ac[c]      = a;
    ac[64 + c] = b[c] - mean * a;
}

// ---- ln: xn = LN(leaky?(affine(u)));  writes fp32 xn + bf16 xnb ---------------
template <int RELU>
__global__ __launch_bounds__(256) void ln_kernel(
    const float* __restrict__ u, const float* __restrict__ ac,
    const float* __restrict__ lng, const float* __restrict__ lnb,
    float* __restrict__ xn, unsigned short* __restrict__ xnb)
{
    const int lane = threadIdx.x & 63;
    const int wid  = (blockIdx.x * 256 + threadIdx.x) >> 6;
    const int nw   = (gridDim.x * 256) >> 6;
    const float a  = ac[lane],  c0 = ac[64 + lane];
    const float g  = lng[lane], bl = lnb[lane];

    for (int row = wid; row < NN; row += nw) {
        float v = u[(size_t)row * 64 + lane];
        v = v * a + c0;
        if (RELU) v = (v > 0.f) ? v : 0.01f * v;
        float s = v;
#pragma unroll
        for (int off = 32; off > 0; off >>= 1) s += __shfl_xor(s, off);
        float mean = s * (1.f / 64.f);
        float d = v - mean;
        float s2 = d * d;
#pragma unroll
        for (int off = 32; off > 0; off >>= 1) s2 += __shfl_xor(s2, off);
        float rstd = rsqrtf(s2 * (1.f / 64.f) + EPSV);
        float o = d * rstd * g + bl;
        xn[(size_t)row * 64 + lane] = o;
        xnb[(size_t)row * 64 + lane] = f2bf(o);
    }
}

// ================= CSR build (graph identical for both layers) ==================
__global__ __launch_bounds__(256) void hist_kernel(
    const int* __restrict__ rowsrc, const int* __restrict__ colsrc,
    int* __restrict__ cnt)
{
    for (int i = blockIdx.x * 256 + threadIdx.x; i < EE; i += gridDim.x * 256) {
        atomicAdd(&cnt[rowsrc[i]], 1);
        atomicAdd(&cnt[NN + colsrc[i]], 1);
    }
}

__global__ __launch_bounds__(256) void scan1_kernel(
    const int* __restrict__ cnt, int* __restrict__ bsum)
{
    const int t = threadIdx.x;
    const int base = blockIdx.x * 1024 + t * 4;
    int s = cnt[base] + cnt[base + 1] + cnt[base + 2] + cnt[base + 3];
    __shared__ int sm[256];
    sm[t] = s;
    __syncthreads();
    for (int off = 1; off < 256; off <<= 1) {
        int v = (t >= off) ? sm[t - off] : 0;
        __syncthreads();
        sm[t] += v;
        __syncthreads();
    }
    if (t == 255) bsum[blockIdx.x] = sm[255];
}

__global__ __launch_bounds__(512) void scan2_kernel(
    const int* __restrict__ bsum, int* __restrict__ bpre, int* __restrict__ ptr)
{
    const int t = threadIdx.x;
    __shared__ int sm[512];
    int orig = bsum[t];
    sm[t] = orig;
    __syncthreads();
    for (int off = 1; off < 512; off <<= 1) {
        int v = (t >= off) ? sm[t - off] : 0;
        __syncthreads();
        sm[t] += v;
        __syncthreads();
    }
    bpre[t] = sm[t] - orig;
    if (t == 0) ptr[NB] = 2 * EE;
}

__global__ __launch_bounds__(256) void scan3_kernel(
    const int* __restrict__ cnt, const int* __restrict__ bpre,
    int* __restrict__ ptr, int* __restrict__ cursor)
{
    const int t = threadIdx.x;
    const int base = blockIdx.x * 1024 + t * 4;
    int c0 = cnt[base], c1 = cnt[base + 1], c2 = cnt[base + 2], c3 = cnt[base + 3];
    int tsum = c0 + c1 + c2 + c3;
    __shared__ int sm[256];
    sm[t] = tsum;
    __syncthreads();
    for (int off = 1; off < 256; off <<= 1) {
        int v = (t >= off) ? sm[t - off] : 0;
        __syncthreads();
        sm[t] += v;
        __syncthreads();
    }
    int p = bpre[blockIdx.x] + sm[t] - tsum;
    ptr[base] = p;     cursor[base] = p;     p += c0;
    ptr[base + 1] = p; cursor[base + 1] = p; p += c1;
    ptr[base + 2] = p; cursor[base + 2] = p; p += c2;
    ptr[base + 3] = p; cursor[base + 3] = p;
}

// ---- windowed fill: 16 windows x 32768 flat-nodes (2.1 MB CSR window each) ----
// Block group x = bid&7 (XCD round-robin heuristic) handles windows {x, x+8}.
// Window < 8 -> row edges only; window >= 8 -> col edges only. All writes for a
// window stay in one XCD's L2 within one pass -> line write-combining.
__global__ __launch_bounds__(256) void fill_win(
    const int* __restrict__ rowsrc, const int* __restrict__ rowdst,
    const float* __restrict__ ratt,
    const int* __restrict__ colsrc, const int* __restrict__ coldst,
    const float* __restrict__ catt,
    int* __restrict__ cursor, int2* __restrict__ edges)
{
    const int x   = blockIdx.x & 7;
    const int sub = blockIdx.x >> 3;
    const int tid = sub * 256 + threadIdx.x;
    const int NT  = (gridDim.x >> 3) * 256;

    // half 0: row edges, window x (flat nodes [x<<15, (x+1)<<15))
    {
        const int w = x;
        for (int i = tid; i < EE; i += NT) {
            int s = rowsrc[i];
            if ((s >> 15) == w) {
                int q = atomicAdd(&cursor[s], 1);
                edges[q] = make_int2(rowdst[i], __float_as_int(ratt[i]));
            }
        }
    }
    // half 1: col edges, window x+8 (flat nodes NN + [x<<15, (x+1)<<15))
    {
        const int w = x + 8;
        for (int i = tid; i < EE; i += NT) {
            int s = NN + colsrc[i];
            if ((s >> 15) == w) {
                int q = atomicAdd(&cursor[s], 1);
                edges[q] = make_int2(coldst[i], __float_as_int(catt[i]));
            }
        }
    }
}

// ---- pure gather: rx[n] = Σ att·xnb[dst] (row), cx[n] = Σ att·xnb[dst] (col) --
__global__ __launch_bounds__(256) void gather_kernel(
    const unsigned short* __restrict__ xnb,
    const int* __restrict__ ptr, const int2* __restrict__ edges,
    unsigned short* __restrict__ rxb, unsigned short* __restrict__ cxb,
    float2* __restrict__ attsum)
{
    const int lane = threadIdx.x & 63;
    const int wid  = (blockIdx.x * 256 + threadIdx.x) >> 6;
    const int nw   = (gridDim.x * 256) >> 6;

    for (int n = wid; n < NN; n += nw) {
        float rx = 0.f, ras = 0.f, cx = 0.f, cas = 0.f;

        int b0 = ptr[n], e0 = ptr[n + 1];
        int i = b0;
        for (; i + 8 <= e0; i += 8) {
            int2 p0 = edges[i],     p1 = edges[i + 1];
            int2 p2 = edges[i + 2], p3 = edges[i + 3];
            int2 p4 = edges[i + 4], p5 = edges[i + 5];
            int2 p6 = edges[i + 6], p7 = edges[i + 7];
            float v0 = bf2f(xnb[(size_t)p0.x * 64 + lane]);
            float v1 = bf2f(xnb[(size_t)p1.x * 64 + lane]);
            float v2 = bf2f(xnb[(size_t)p2.x * 64 + lane]);
            float v3 = bf2f(xnb[(size_t)p3.x * 64 + lane]);
            float v4 = bf2f(xnb[(size_t)p4.x * 64 + lane]);
            float v5 = bf2f(xnb[(size_t)p5.x * 64 + lane]);
            float v6 = bf2f(xnb[(size_t)p6.x * 64 + lane]);
            float v7 = bf2f(xnb[(size_t)p7.x * 64 + lane]);
            float a0 = __int_as_float(p0.y), a1 = __int_as_float(p1.y);
            float a2 = __int_as_float(p2.y), a3 = __int_as_float(p3.y);
            float a4 = __int_as_float(p4.y), a5 = __int_as_float(p5.y);
            float a6 = __int_as_float(p6.y), a7 = __int_as_float(p7.y);
            rx = fmaf(v0, a0, rx); ras += a0;
            rx = fmaf(v1, a1, rx); ras += a1;
            rx = fmaf(v2, a2, rx); ras += a2;
            rx = fmaf(v3, a3, rx); ras += a3;
            rx = fmaf(v4, a4, rx); ras += a4;
            rx = fmaf(v5, a5, rx); ras += a5;
            rx = fmaf(v6, a6, rx); ras += a6;
            rx = fmaf(v7, a7, rx); ras += a7;
        }
        for (; i < e0; ++i) {
            int2 p = edges[i];
            float a = __int_as_float(p.y);
            rx = fmaf(bf2f(xnb[(size_t)p.x * 64 + lane]), a, rx);
            ras += a;
        }

        int b1 = ptr[NN + n], e1 = ptr[NN + n + 1];
        i = b1;
        for (; i + 8 <= e1; i += 8) {
            int2 p0 = edges[i],     p1 = edges[i + 1];
            int2 p2 = edges[i + 2], p3 = edges[i + 3];
            int2 p4 = edges[i + 4], p5 = edges[i + 5];
            int2 p6 = edges[i + 6], p7 = edges[i + 7];
            float v0 = bf2f(xnb[(size_t)p0.x * 64 + lane]);
            float v1 = bf2f(xnb[(size_t)p1.x * 64 + lane]);
            float v2 = bf2f(xnb[(size_t)p2.x * 64 + lane]);
            float v3 = bf2f(xnb[(size_t)p3.x * 64 + lane]);
            float v4 = bf2f(xnb[(size_t)p4.x * 64 + lane]);
            float v5 = bf2f(xnb[(size_t)p5.x * 64 + lane]);
            float v6 = bf2f(xnb[(size_t)p6.x * 64 + lane]);
            float v7 = bf2f(xnb[(size_t)p7.x * 64 + lane]);
            float a0 = __int_as_float(p0.y), a1 = __int_as_float(p1.y);
            float a2 = __int_as_float(p2.y), a3 = __int_as_float(p3.y);
            float a4 = __int_as_float(p4.y), a5 = __int_as_float(p5.y);
            float a6 = __int_as_float(p6.y), a7 = __int_as_float(p7.y);
            cx = fmaf(v0, a0, cx); cas += a0;
            cx = fmaf(v1, a1, cx); cas += a1;
            cx = fmaf(v2, a2, cx); cas += a2;
            cx = fmaf(v3, a3, cx); cas += a3;
            cx = fmaf(v4, a4, cx); cas += a4;
            cx = fmaf(v5, a5, cx); cas += a5;
            cx = fmaf(v6, a6, cx); cas += a6;
            cx = fmaf(v7, a7, cx); cas += a7;
        }
        for (; i < e1; ++i) {
            int2 p = edges[i];
            float a = __int_as_float(p.y);
            cx = fmaf(bf2f(xnb[(size_t)p.x * 64 + lane]), a, cx);
            cas += a;
        }

        rxb[(size_t)n * 64 + lane] = f2bf(rx);
        cxb[(size_t)n * 64 + lane] = f2bf(cx);
        if (lane == 0) attsum[n] = make_float2(ras, cas);
    }
}

// ---- weight pre-swizzle into MFMA B-fragment layout (bf16) --------------------
__global__ __launch_bounds__(256) void w_convert(
    const float* __restrict__ Wrv, const float* __restrict__ Wcv,
    unsigned short* __restrict__ wbuf)
{
    int idx = blockIdx.x * 256 + threadIdx.x;   // 0..16383
    int e    = idx & 7;
    int lane = (idx >> 3) & 63;
    int t    = (idx >> 9) & 3;
    int kb   = (idx >> 11) & 1;
    int m    = (idx >> 12) & 1;
    int L    = (idx >> 13) & 1;
    const float* W = (m ? Wcv : Wrv) + L * 4096;
    float w = W[(kb * 32 + ((lane >> 4) & 3) * 8 + e) * 64 + t * 16 + (lane & 15)];
    wbuf[idx] = f2bf(w);
}

// ---- MFMA epilogue: out = xn + rx@Wr + cx@Wc + ras·br + cas·bc; fused stats ---
__global__ __launch_bounds__(256) void gemv_mfma(
    const unsigned short* __restrict__ rxb, const unsigned short* __restrict__ cxb,
    const float* __restrict__ xn, const float2* __restrict__ attsum,
    const unsigned short* __restrict__ wb16,
    const float* __restrict__ br, const float* __restrict__ bc,
    float* __restrict__ out, float* __restrict__ stats)
{
    const int lane = threadIdx.x & 63;
    const int wloc = threadIdx.x >> 6;
    const int wid  = (blockIdx.x * 256 + threadIdx.x) >> 6;
    const int nw   = (gridDim.x * 256) >> 6;
    const int lo   = lane & 15;
    const int hi   = lane >> 4;

    const bf16x8* wb = (const bf16x8*)wb16;
    bf16x8 bfr[2][2][4];
#pragma unroll
    for (int m = 0; m < 2; ++m)
#pragma unroll
        for (int kb = 0; kb < 2; ++kb)
#pragma unroll
            for (int t = 0; t < 4; ++t)
                bfr[m][kb][t] = wb[((m * 2 + kb) * 4 + t) * 64 + lane];

    float brv4[4], bcv4[4];
#pragma unroll
    for (int t = 0; t < 4; ++t) {
        brv4[t] = br[t * 16 + lo];
        bcv4[t] = bc[t * 16 + lo];
    }

    float ss[4] = {0.f, 0.f, 0.f, 0.f}, ss2[4] = {0.f, 0.f, 0.f, 0.f};
    const bf16x8* ra = (const bf16x8*)rxb;
    const bf16x8* ca = (const bf16x8*)cxb;

    for (int tile = wid; tile < NN / 16; tile += nw) {
        const int n0 = tile * 16;
        const int arow = n0 + lo;
        bf16x8 a0 = ra[arow * 8 + hi];
        bf16x8 a1 = ra[arow * 8 + 4 + hi];
        bf16x8 c0 = ca[arow * 8 + hi];
        bf16x8 c1 = ca[arow * 8 + 4 + hi];
        float2 an[4];
#pragma unroll
        for (int r = 0; r < 4; ++r) an[r] = attsum[n0 + hi * 4 + r];

#pragma unroll
        for (int t = 0; t < 4; ++t) {
            f32x4 acc = {0.f, 0.f, 0.f, 0.f};
            acc = __builtin_amdgcn_mfma_f32_16x16x32_bf16(a0, bfr[0][0][t], acc, 0, 0, 0);
            acc = __builtin_amdgcn_mfma_f32_16x16x32_bf16(a1, bfr[0][1][t], acc, 0, 0, 0);
            acc = __builtin_amdgcn_mfma_f32_16x16x32_bf16(c0, bfr[1][0][t], acc, 0, 0, 0);
            acc = __builtin_amdgcn_mfma_f32_16x16x32_bf16(c1, bfr[1][1][t], acc, 0, 0, 0);
            const int col = t * 16 + lo;
#pragma unroll
            for (int r = 0; r < 4; ++r) {
                const int n = n0 + hi * 4 + r;
                float v = acc[r] + xn[(size_t)n * 64 + col]
                        + an[r].x * brv4[t] + an[r].y * bcv4[t];
                out[(size_t)n * 64 + col] = v;
                ss[t] += v;
                ss2[t] += v * v;
            }
        }
    }

    // stats reduce: lanes sharing the same (lane&15) hold the same channels
#pragma unroll
    for (int t = 0; t < 4; ++t) {
        ss[t]  += __shfl_xor(ss[t], 16);  ss[t]  += __shfl_xor(ss[t], 32);
        ss2[t] += __shfl_xor(ss2[t], 16); ss2[t] += __shfl_xor(ss2[t], 32);
    }
    __shared__ float ls[4][64], ls2[4][64];
    if (lo == lane) {   // lanes 0..15
#pragma unroll
        for (int t = 0; t < 4; ++t) {
            ls[wloc][t * 16 + lane]  = ss[t];
            ls2[wloc][t * 16 + lane] = ss2[t];
        }
    }
    __syncthreads();
    if (threadIdx.x < 64) {
        int ch = threadIdx.x;
        atomicAdd(&stats[ch],      ls[0][ch] + ls[1][ch] + ls[2][ch] + ls[3][ch]);
        atomicAdd(&stats[64 + ch], ls2[0][ch] + ls2[1][ch] + ls2[2][ch] + ls2[3][ch]);
    }
}

// ------ fused output: affine+leaky -> logits = h@smW + b -> softmax ------------
__global__ __launch_bounds__(256) void out_kernel(
    const float* __restrict__ agg, const float* __restrict__ ac,
    const float* __restrict__ smW, const float* __restrict__ smb,
    float* __restrict__ out)
{
    __shared__ float sW[64 * 16];
    for (int i = threadIdx.x; i < 64 * 16; i += 256) sW[i] = smW[i];
    __syncthreads();
    const int j = threadIdx.x & 15;
    const int rloc = threadIdx.x >> 4;
    const float bj = smb[j];
    for (int row = blockIdx.x * 16 + rloc; row < NN; row += gridDim.x * 16) {
        float acc = bj;
#pragma unroll
        for (int k = 0; k < 64; ++k) {
            float v = agg[(size_t)row * 64 + k];
            v = v * ac[k] + ac[64 + k];
            v = (v > 0.f) ? v : 0.01f * v;
            acc = fmaf(v, sW[k * 16 + j], acc);
        }
        float m = acc;
#pragma unroll
        for (int off = 8; off > 0; off >>= 1) m = fmaxf(m, __shfl_xor(m, off));
        float e = expf(acc - m);
        float ssum = e;
#pragma unroll
        for (int off = 8; off > 0; off >>= 1) ssum += __shfl_xor(ssum, off);
        out[(size_t)row * 16 + j] = e / ssum;
    }
}

// ------------------------------------------------------------------------------
extern "C" void kernel_launch(void* const* d_in, const int* in_sizes, int n_in,
                              void* d_out, int out_size, void* d_ws, size_t ws_size,
                              hipStream_t stream)
{
    const float* x        = (const float*)d_in[0];
    const float* row_att  = (const float*)d_in[1];
    const float* col_att  = (const float*)d_in[2];
    const float* prelin_W = (const float*)d_in[3];
    const float* prelin_b = (const float*)d_in[4];
    const float* bn0_g    = (const float*)d_in[5];
    const float* bn0_b    = (const float*)d_in[6];
    const float* ln_g     = (const float*)d_in[7];
    const float* ln_b     = (const float*)d_in[8];
    const float* Wrv      = (const float*)d_in[9];
    const float* brv      = (const float*)d_in[10];
    const float* Wcv      = (const float*)d_in[11];
    const float* bcv      = (const float*)d_in[12];
    const float* bn_g     = (const float*)d_in[13];
    const float* bn_b     = (const float*)d_in[14];
    const float* sm_W     = (const float*)d_in[15];
    const float* sm_b     = (const float*)d_in[16];
    const int*   rowsrc   = (const int*)d_in[17];
    const int*   rowdst   = (const int*)d_in[18];
    const int*   colsrc   = (const int*)d_in[19];
    const int*   coldst   = (const int*)d_in[20];
    float* out = (float*)d_out;

    // ---- workspace layout (~245 MB) ----
    const size_t NH = (size_t)NN * 64;
    float* A  = (float*)d_ws;                    // stem out / layer out
    float* xn = A + NH;                          // fp32 LN output (residual)

    char* extra = (char*)(xn + NH);
    unsigned short* xnb = (unsigned short*)extra; extra += NH * sizeof(short);
    unsigned short* rxb = (unsigned short*)extra; extra += NH * sizeof(short);
    unsigned short* cxb = (unsigned short*)extra; extra += NH * sizeof(short);
    float2* attsum = (float2*)extra;              extra += (size_t)NN * sizeof(float2);
    float* stats  = (float*)extra;                extra += 3 * 128 * sizeof(float);
    float* ac     = (float*)extra;                extra += 3 * 128 * sizeof(float);
    unsigned short* wbuf = (unsigned short*)extra; extra += 16384 * sizeof(short);
    int*   bsum   = (int*)extra;                  extra += 512 * sizeof(int);
    int*   bpre   = (int*)extra;                  extra += 512 * sizeof(int);
    int*   ptr    = (int*)extra;                  extra += (NB + 1) * sizeof(int);
    int*   counts = (int*)extra;                  extra += NB * sizeof(int);
    int*   cursor = (int*)extra;                  extra += NB * sizeof(int);
    int2*  edges  = (int2*)extra;                 extra += 2 * (size_t)EE * sizeof(int2);

    hipMemsetAsync(stats, 0, 3 * 128 * sizeof(float), stream);
    hipMemsetAsync(counts, 0, NB * sizeof(int), stream);

    // ---- CSR build (used by both layers) ----
    hist_kernel<<<2048, 256, 0, stream>>>(rowsrc, colsrc, counts);
    scan1_kernel<<<512, 256, 0, stream>>>(counts, bsum);
    scan2_kernel<<<1, 512, 0, stream>>>(bsum, bpre, ptr);
    scan3_kernel<<<512, 256, 0, stream>>>(counts, bpre, ptr, cursor);
    fill_win<<<2048, 256, 0, stream>>>(rowsrc, rowdst, row_att,
                                       colsrc, coldst, col_att,
                                       cursor, edges);
    w_convert<<<64, 256, 0, stream>>>(Wrv, Wcv, wbuf);

    // ---- stem ----
    stem_gemm<<<NN / 64, 256, 0, stream>>>(x, prelin_W, prelin_b, A);
    stats_kernel<<<1024, 256, 0, stream>>>(A, stats);
    finalize_bn<<<1, 64, 0, stream>>>(stats, bn0_g, bn0_b, ac);

    // ---- layer 0 ----
    ln_kernel<0><<<4096, 256, 0, stream>>>(A, ac, ln_g, ln_b, xn, xnb);
    gather_kernel<<<8192, 256, 0, stream>>>(xnb, ptr, edges, rxb, cxb, attsum);
    gemv_mfma<<<1024, 256, 0, stream>>>(rxb, cxb, xn, attsum, wbuf,
                                        brv, bcv, A, stats + 128);
    finalize_bn<<<1, 64, 0, stream>>>(stats + 128, bn_g, bn_b, ac + 128);

    // ---- layer 1 ----
    ln_kernel<1><<<4096, 256, 0, stream>>>(A, ac + 128, ln_g + 64, ln_b + 64, xn, xnb);
    gather_kernel<<<8192, 256, 0, stream>>>(xnb, ptr, edges, rxb, cxb, attsum);
    gemv_mfma<<<1024, 256, 0, stream>>>(rxb, cxb, xn, attsum, wbuf + 8192,
                                        brv + 64, bcv + 64, A, stats + 256);
    finalize_bn<<<1, 64, 0, stream>>>(stats + 256, bn_g + 64, bn_b + 64, ac + 256);

    // ---- output head ----
    out_kernel<<<2048, 256, 0, stream>>>(A, ac + 256, sm_W, sm_b, out);
}

// Round 9
// 1357.965 us; speedup vs baseline: 1.5191x; 1.0102x over previous
//
#include <hip/hip_runtime.h>
#include <math.h>

#define NN   262144      // nodes
#define CIN  200         // input channels
#define EE   2097152     // edges
#define NB   (2*NN)      // flat count/ptr sections: [row | col]
#define EPSV 1e-5f

typedef __bf16 bf16x8 __attribute__((ext_vector_type(8)));
typedef float  f32x4  __attribute__((ext_vector_type(4)));

__device__ __forceinline__ unsigned short f2bf(float f) {
    unsigned int u = __float_as_uint(f);
    unsigned int r = (u + 0x7fffu + ((u >> 16) & 1u)) >> 16;
    return (unsigned short)r;
}
__device__ __forceinline__ float bf2f(unsigned short u) {
    return __uint_as_float(((unsigned int)u) << 16);
}

// ---------------- stem GEMM: t = x @ W + b   ([N,200] @ [200,64]) --------------
__global__ __launch_bounds__(256) void stem_gemm(
    const float* __restrict__ x, const float* __restrict__ W,
    const float* __restrict__ bias, float* __restrict__ t)
{
    __shared__ float sA[40][64];
    __shared__ float sB[40][64];
    const int tid = threadIdx.x;
    const int rid = tid >> 4;
    const int cid = tid & 15;
    const int row0 = blockIdx.x * 64;

    float acc[4][4];
#pragma unroll
    for (int i = 0; i < 4; ++i)
#pragma unroll
        for (int j = 0; j < 4; ++j) acc[i][j] = 0.f;

    for (int k0 = 0; k0 < CIN; k0 += 40) {
        __syncthreads();
        for (int idx = tid; idx < 64 * 40; idx += 256) {
            int r = idx / 40, kk = idx % 40;
            sA[kk][r] = x[(size_t)(row0 + r) * CIN + k0 + kk];
        }
        for (int idx = tid; idx < 40 * 64; idx += 256) {
            int kk = idx >> 6, c = idx & 63;
            sB[kk][c] = W[(k0 + kk) * 64 + c];
        }
        __syncthreads();
#pragma unroll
        for (int kk = 0; kk < 40; ++kk) {
            const float4 a4 = *(const float4*)&sA[kk][rid * 4];
            const float4 b4 = *(const float4*)&sB[kk][cid * 4];
            acc[0][0] = fmaf(a4.x, b4.x, acc[0][0]);
            acc[0][1] = fmaf(a4.x, b4.y, acc[0][1]);
            acc[0][2] = fmaf(a4.x, b4.z, acc[0][2]);
            acc[0][3] = fmaf(a4.x, b4.w, acc[0][3]);
            acc[1][0] = fmaf(a4.y, b4.x, acc[1][0]);
            acc[1][1] = fmaf(a4.y, b4.y, acc[1][1]);
            acc[1][2] = fmaf(a4.y, b4.z, acc[1][2]);
            acc[1][3] = fmaf(a4.y, b4.w, acc[1][3]);
            acc[2][0] = fmaf(a4.z, b4.x, acc[2][0]);
            acc[2][1] = fmaf(a4.z, b4.y, acc[2][1]);
            acc[2][2] = fmaf(a4.z, b4.z, acc[2][2]);
            acc[2][3] = fmaf(a4.z, b4.w, acc[2][3]);
            acc[3][0] = fmaf(a4.w, b4.x, acc[3][0]);
            acc[3][1] = fmaf(a4.w, b4.y, acc[3][1]);
            acc[3][2] = fmaf(a4.w, b4.z, acc[3][2]);
            acc[3][3] = fmaf(a4.w, b4.w, acc[3][3]);
        }
    }
    const float4 bb = *(const float4*)&bias[cid * 4];
#pragma unroll
    for (int i = 0; i < 4; ++i) {
        float4 o;
        o.x = acc[i][0] + bb.x;
        o.y = acc[i][1] + bb.y;
        o.z = acc[i][2] + bb.z;
        o.w = acc[i][3] + bb.w;
        *(float4*)&t[(size_t)(row0 + rid * 4 + i) * 64 + cid * 4] = o;
    }
}

// ---------------- per-channel batch stats (stem only) --------------------------
__global__ __launch_bounds__(256) void stats_kernel(
    const float* __restrict__ src, float* __restrict__ stats)
{
    const int c = threadIdx.x & 63;
    const int rg = threadIdx.x >> 6;
    float s = 0.f, s2 = 0.f;
    for (int row = blockIdx.x * 4 + rg; row < NN; row += gridDim.x * 4) {
        float v = src[(size_t)row * 64 + c];
        s += v;
        s2 += v * v;
    }
    __shared__ float ls[4][64], ls2[4][64];
    ls[rg][c] = s;
    ls2[rg][c] = s2;
    __syncthreads();
    if (threadIdx.x < 64) {
        atomicAdd(&stats[c],      ls[0][c] + ls[1][c] + ls[2][c] + ls[3][c]);
        atomicAdd(&stats[64 + c], ls2[0][c] + ls2[1][c] + ls2[2][c] + ls2[3][c]);
    }
}

// fold BN into per-channel affine:  bn(v) = v*a + c
__global__ void finalize_bn(const float* __restrict__ stats,
                            const float* __restrict__ g, const float* __restrict__ b,
                            float* __restrict__ ac)
{
    int c = threadIdx.x;
    float mean = stats[c] * (1.f / NN);
    float var  = stats[64 + c] * (1.f / NN) - mean * mean;
    float rstd = rsqrtf(var + EPSV);
    float a = g[c] * rstd;
    ac[c]      = a;
    ac[64 + c] = b[c] - mean * a;
}

// ---- ln: xn = LN(leaky?(affine(u)));  writes fp32 xn + bf16 xnb ---------------
template <int RELU>
__global__ __launch_bounds__(256) void ln_kernel(
    const float* __restrict__ u, const float* __restrict__ ac,
    const float* __restrict__ lng, const float* __restrict__ lnb,
    float* __restrict__ xn, unsigned short* __restrict__ xnb)
{
    const int lane = threadIdx.x & 63;
    const int wid  = (blockIdx.x * 256 + threadIdx.x) >> 6;
    const int nw   = (gridDim.x * 256) >> 6;
    const float a  = ac[lane],  c0 = ac[64 + lane];
    const float g  = lng[lane], bl = lnb[lane];

    for (int row = wid; row < NN; row += nw) {
        float v = u[(size_t)row * 64 + lane];
        v = v * a + c0;
        if (RELU) v = (v > 0.f) ? v : 0.01f * v;
        float s = v;
#pragma unroll
        for (int off = 32; off > 0; off >>= 1) s += __shfl_xor(s, off);
        float mean = s * (1.f / 64.f);
        float d = v - mean;
        float s2 = d * d;
#pragma unroll
        for (int off = 32; off > 0; off >>= 1) s2 += __shfl_xor(s2, off);
        float rstd = rsqrtf(s2 * (1.f / 64.f) + EPSV);
        float o = d * rstd * g + bl;
        xn[(size_t)row * 64 + lane] = o;
        xnb[(size_t)row * 64 + lane] = f2bf(o);
    }
}

// ================= CSR build (graph identical for both layers) ==================
__global__ __launch_bounds__(256) void hist_kernel(
    const int* __restrict__ rowsrc, const int* __restrict__ colsrc,
    int* __restrict__ cnt)
{
    for (int i = blockIdx.x * 256 + threadIdx.x; i < EE; i += gridDim.x * 256) {
        atomicAdd(&cnt[rowsrc[i]], 1);
        atomicAdd(&cnt[NN + colsrc[i]], 1);
    }
}

__global__ __launch_bounds__(256) void scan1_kernel(
    const int* __restrict__ cnt, int* __restrict__ bsum)
{
    const int t = threadIdx.x;
    const int base = blockIdx.x * 1024 + t * 4;
    int s = cnt[base] + cnt[base + 1] + cnt[base + 2] + cnt[base + 3];
    __shared__ int sm[256];
    sm[t] = s;
    __syncthreads();
    for (int off = 1; off < 256; off <<= 1) {
        int v = (t >= off) ? sm[t - off] : 0;
        __syncthreads();
        sm[t] += v;
        __syncthreads();
    }
    if (t == 255) bsum[blockIdx.x] = sm[255];
}

__global__ __launch_bounds__(512) void scan2_kernel(
    const int* __restrict__ bsum, int* __restrict__ bpre, int* __restrict__ ptr)
{
    const int t = threadIdx.x;
    __shared__ int sm[512];
    int orig = bsum[t];
    sm[t] = orig;
    __syncthreads();
    for (int off = 1; off < 512; off <<= 1) {
        int v = (t >= off) ? sm[t - off] : 0;
        __syncthreads();
        sm[t] += v;
        __syncthreads();
    }
    bpre[t] = sm[t] - orig;
    if (t == 0) ptr[NB] = 2 * EE;
}

__global__ __launch_bounds__(256) void scan3_kernel(
    const int* __restrict__ cnt, const int* __restrict__ bpre,
    int* __restrict__ ptr, int* __restrict__ cursor)
{
    const int t = threadIdx.x;
    const int base = blockIdx.x * 1024 + t * 4;
    int c0 = cnt[base], c1 = cnt[base + 1], c2 = cnt[base + 2], c3 = cnt[base + 3];
    int tsum = c0 + c1 + c2 + c3;
    __shared__ int sm[256];
    sm[t] = tsum;
    __syncthreads();
    for (int off = 1; off < 256; off <<= 1) {
        int v = (t >= off) ? sm[t - off] : 0;
        __syncthreads();
        sm[t] += v;
        __syncthreads();
    }
    int p = bpre[blockIdx.x] + sm[t] - tsum;
    ptr[base] = p;     cursor[base] = p;     p += c0;
    ptr[base + 1] = p; cursor[base + 1] = p; p += c1;
    ptr[base + 2] = p; cursor[base + 2] = p; p += c2;
    ptr[base + 3] = p; cursor[base + 3] = p;
}

// ---- windowed fill: 16 windows x 32768 flat-nodes (2.1 MB CSR window each) ----
__global__ __launch_bounds__(256) void fill_win(
    const int* __restrict__ rowsrc, const int* __restrict__ rowdst,
    const float* __restrict__ ratt,
    const int* __restrict__ colsrc, const int* __restrict__ coldst,
    const float* __restrict__ catt,
    int* __restrict__ cursor, int2* __restrict__ edges)
{
    const int x   = blockIdx.x & 7;
    const int sub = blockIdx.x >> 3;
    const int tid = sub * 256 + threadIdx.x;
    const int NT  = (gridDim.x >> 3) * 256;

    // half 0: row edges, window x (flat nodes [x<<15, (x+1)<<15))
    {
        const int w = x;
        for (int i = tid; i < EE; i += NT) {
            int s = rowsrc[i];
            if ((s >> 15) == w) {
                int q = atomicAdd(&cursor[s], 1);
                edges[q] = make_int2(rowdst[i], __float_as_int(ratt[i]));
            }
        }
    }
    // half 1: col edges, window x+8 (flat nodes NN + [x<<15, (x+1)<<15))
    {
        const int w = x + 8;
        for (int i = tid; i < EE; i += NT) {
            int s = NN + colsrc[i];
            if ((s >> 15) == w) {
                int q = atomicAdd(&cursor[s], 1);
                edges[q] = make_int2(coldst[i], __float_as_int(catt[i]));
            }
        }
    }
}

// ---- pure gather, 4 concurrent streams per wave (node pair x row/col) ---------
// All loads unconditional (clamped index); contribution masked via att=0 select.
__global__ __launch_bounds__(256) void gather_kernel(
    const unsigned short* __restrict__ xnb,
    const int* __restrict__ ptr, const int2* __restrict__ edges,
    unsigned short* __restrict__ rxb, unsigned short* __restrict__ cxb,
    float2* __restrict__ attsum)
{
    const int lane = threadIdx.x & 63;
    const int wid  = (blockIdx.x * 256 + threadIdx.x) >> 6;
    const int nw   = (gridDim.x * 256) >> 6;
    const int HALF = NN / 2;

    for (int n = wid; n < HALF; n += nw) {
        const int m = n + HALF;
        const int i0 = ptr[n],      e0 = ptr[n + 1];
        const int i1 = ptr[NN + n], e1 = ptr[NN + n + 1];
        const int i2 = ptr[m],      e2 = ptr[m + 1];
        const int i3 = ptr[NN + m], e3 = ptr[NN + m + 1];
        const int len0 = e0 - i0, len1 = e1 - i1, len2 = e2 - i2, len3 = e3 - i3;
        int maxlen = max(max(len0, len1), max(len2, len3));

        float rx0 = 0.f, cx0 = 0.f, rx1 = 0.f, cx1 = 0.f;
        float ras0 = 0.f, cas0 = 0.f, ras1 = 0.f, cas1 = 0.f;

#pragma unroll 2
        for (int k = 0; k < maxlen; ++k) {
            // unconditional loads from clamped indices; mask via a=0
            int j0 = min(i0 + ((k < len0) ? k : 0), 2 * EE - 1);
            int j1 = min(i1 + ((k < len1) ? k : 0), 2 * EE - 1);
            int j2 = min(i2 + ((k < len2) ? k : 0), 2 * EE - 1);
            int j3 = min(i3 + ((k < len3) ? k : 0), 2 * EE - 1);
            int2 p0 = edges[j0];
            int2 p1 = edges[j1];
            int2 p2 = edges[j2];
            int2 p3 = edges[j3];
            float v0 = bf2f(xnb[(size_t)p0.x * 64 + lane]);
            float v1 = bf2f(xnb[(size_t)p1.x * 64 + lane]);
            float v2 = bf2f(xnb[(size_t)p2.x * 64 + lane]);
            float v3 = bf2f(xnb[(size_t)p3.x * 64 + lane]);
            float a0 = (k < len0) ? __int_as_float(p0.y) : 0.f;
            float a1 = (k < len1) ? __int_as_float(p1.y) : 0.f;
            float a2 = (k < len2) ? __int_as_float(p2.y) : 0.f;
            float a3 = (k < len3) ? __int_as_float(p3.y) : 0.f;
            rx0 = fmaf(v0, a0, rx0); ras0 += a0;
            cx0 = fmaf(v1, a1, cx0); cas0 += a1;
            rx1 = fmaf(v2, a2, rx1); ras1 += a2;
            cx1 = fmaf(v3, a3, cx1); cas1 += a3;
        }

        rxb[(size_t)n * 64 + lane] = f2bf(rx0);
        cxb[(size_t)n * 64 + lane] = f2bf(cx0);
        rxb[(size_t)m * 64 + lane] = f2bf(rx1);
        cxb[(size_t)m * 64 + lane] = f2bf(cx1);
        if (lane == 0) {
            attsum[n] = make_float2(ras0, cas0);
            attsum[m] = make_float2(ras1, cas1);
        }
    }
}

// ---- weight pre-swizzle into MFMA B-fragment layout (bf16) --------------------
__global__ __launch_bounds__(256) void w_convert(
    const float* __restrict__ Wrv, const float* __restrict__ Wcv,
    unsigned short* __restrict__ wbuf)
{
    int idx = blockIdx.x * 256 + threadIdx.x;   // 0..16383
    int e    = idx & 7;
    int lane = (idx >> 3) & 63;
    int t    = (idx >> 9) & 3;
    int kb   = (idx >> 11) & 1;
    int m    = (idx >> 12) & 1;
    int L    = (idx >> 13) & 1;
    const float* W = (m ? Wcv : Wrv) + L * 4096;
    float w = W[(kb * 32 + ((lane >> 4) & 3) * 8 + e) * 64 + t * 16 + (lane & 15)];
    wbuf[idx] = f2bf(w);
}

// ---- MFMA epilogue: out = xn + rx@Wr + cx@Wc + ras·br + cas·bc; fused stats ---
__global__ __launch_bounds__(256) void gemv_mfma(
    const unsigned short* __restrict__ rxb, const unsigned short* __restrict__ cxb,
    const float* __restrict__ xn, const float2* __restrict__ attsum,
    const unsigned short* __restrict__ wb16,
    const float* __restrict__ br, const float* __restrict__ bc,
    float* __restrict__ out, float* __restrict__ stats)
{
    const int lane = threadIdx.x & 63;
    const int wloc = threadIdx.x >> 6;
    const int wid  = (blockIdx.x * 256 + threadIdx.x) >> 6;
    const int nw   = (gridDim.x * 256) >> 6;
    const int lo   = lane & 15;
    const int hi   = lane >> 4;

    const bf16x8* wb = (const bf16x8*)wb16;
    bf16x8 bfr[2][2][4];
#pragma unroll
    for (int m = 0; m < 2; ++m)
#pragma unroll
        for (int kb = 0; kb < 2; ++kb)
#pragma unroll
            for (int t = 0; t < 4; ++t)
                bfr[m][kb][t] = wb[((m * 2 + kb) * 4 + t) * 64 + lane];

    float brv4[4], bcv4[4];
#pragma unroll
    for (int t = 0; t < 4; ++t) {
        brv4[t] = br[t * 16 + lo];
        bcv4[t] = bc[t * 16 + lo];
    }

    float ss[4] = {0.f, 0.f, 0.f, 0.f}, ss2[4] = {0.f, 0.f, 0.f, 0.f};
    const bf16x8* ra = (const bf16x8*)rxb;
    const bf16x8* ca = (const bf16x8*)cxb;

    for (int tile = wid; tile < NN / 16; tile += nw) {
        const int n0 = tile * 16;
        const int arow = n0 + lo;
        bf16x8 a0 = ra[arow * 8 + hi];
        bf16x8 a1 = ra[arow * 8 + 4 + hi];
        bf16x8 c0 = ca[arow * 8 + hi];
        bf16x8 c1 = ca[arow * 8 + 4 + hi];
        float2 an[4];
#pragma unroll
        for (int r = 0; r < 4; ++r) an[r] = attsum[n0 + hi * 4 + r];

#pragma unroll
        for (int t = 0; t < 4; ++t) {
            f32x4 acc = {0.f, 0.f, 0.f, 0.f};
            acc = __builtin_amdgcn_mfma_f32_16x16x32_bf16(a0, bfr[0][0][t], acc, 0, 0, 0);
            acc = __builtin_amdgcn_mfma_f32_16x16x32_bf16(a1, bfr[0][1][t], acc, 0, 0, 0);
            acc = __builtin_amdgcn_mfma_f32_16x16x32_bf16(c0, bfr[1][0][t], acc, 0, 0, 0);
            acc = __builtin_amdgcn_mfma_f32_16x16x32_bf16(c1, bfr[1][1][t], acc, 0, 0, 0);
            const int col = t * 16 + lo;
#pragma unroll
            for (int r = 0; r < 4; ++r) {
                const int n = n0 + hi * 4 + r;
                float v = acc[r] + xn[(size_t)n * 64 + col]
                        + an[r].x * brv4[t] + an[r].y * bcv4[t];
                out[(size_t)n * 64 + col] = v;
                ss[t] += v;
                ss2[t] += v * v;
            }
        }
    }

    // stats reduce: lanes sharing the same (lane&15) hold the same channels
#pragma unroll
    for (int t = 0; t < 4; ++t) {
        ss[t]  += __shfl_xor(ss[t], 16);  ss[t]  += __shfl_xor(ss[t], 32);
        ss2[t] += __shfl_xor(ss2[t], 16); ss2[t] += __shfl_xor(ss2[t], 32);
    }
    __shared__ float ls[4][64], ls2[4][64];
    if (lo == lane) {   // lanes 0..15
#pragma unroll
        for (int t = 0; t < 4; ++t) {
            ls[wloc][t * 16 + lane]  = ss[t];
            ls2[wloc][t * 16 + lane] = ss2[t];
        }
    }
    __syncthreads();
    if (threadIdx.x < 64) {
        int ch = threadIdx.x;
        atomicAdd(&stats[ch],      ls[0][ch] + ls[1][ch] + ls[2][ch] + ls[3][ch]);
        atomicAdd(&stats[64 + ch], ls2[0][ch] + ls2[1][ch] + ls2[2][ch] + ls2[3][ch]);
    }
}

// ------ fused output: affine+leaky -> logits = h@smW + b -> softmax ------------
__global__ __launch_bounds__(256) void out_kernel(
    const float* __restrict__ agg, const float* __restrict__ ac,
    const float* __restrict__ smW, const float* __restrict__ smb,
    float* __restrict__ out)
{
    __shared__ float sW[64 * 16];
    for (int i = threadIdx.x; i < 64 * 16; i += 256) sW[i] = smW[i];
    __syncthreads();
    const int j = threadIdx.x & 15;
    const int rloc = threadIdx.x >> 4;
    const float bj = smb[j];
    for (int row = blockIdx.x * 16 + rloc; row < NN; row += gridDim.x * 16) {
        float acc = bj;
#pragma unroll
        for (int k = 0; k < 64; ++k) {
            float v = agg[(size_t)row * 64 + k];
            v = v * ac[k] + ac[64 + k];
            v = (v > 0.f) ? v : 0.01f * v;
            acc = fmaf(v, sW[k * 16 + j], acc);
        }
        float m = acc;
#pragma unroll
        for (int off = 8; off > 0; off >>= 1) m = fmaxf(m, __shfl_xor(m, off));
        float e = expf(acc - m);
        float ssum = e;
#pragma unroll
        for (int off = 8; off > 0; off >>= 1) ssum += __shfl_xor(ssum, off);
        out[(size_t)row * 16 + j] = e / ssum;
    }
}

// ------------------------------------------------------------------------------
extern "C" void kernel_launch(void* const* d_in, const int* in_sizes, int n_in,
                              void* d_out, int out_size, void* d_ws, size_t ws_size,
                              hipStream_t stream)
{
    const float* x        = (const float*)d_in[0];
    const float* row_att  = (const float*)d_in[1];
    const float* col_att  = (const float*)d_in[2];
    const float* prelin_W = (const float*)d_in[3];
    const float* prelin_b = (const float*)d_in[4];
    const float* bn0_g    = (const float*)d_in[5];
    const float* bn0_b    = (const float*)d_in[6];
    const float* ln_g     = (const float*)d_in[7];
    const float* ln_b     = (const float*)d_in[8];
    const float* Wrv      = (const float*)d_in[9];
    const float* brv      = (const float*)d_in[10];
    const float* Wcv      = (const float*)d_in[11];
    const float* bcv      = (const float*)d_in[12];
    const float* bn_g     = (const float*)d_in[13];
    const float* bn_b     = (const float*)d_in[14];
    const float* sm_W     = (const float*)d_in[15];
    const float* sm_b     = (const float*)d_in[16];
    const int*   rowsrc   = (const int*)d_in[17];
    const int*   rowdst   = (const int*)d_in[18];
    const int*   colsrc   = (const int*)d_in[19];
    const int*   coldst   = (const int*)d_in[20];
    float* out = (float*)d_out;

    // ---- workspace layout (~245 MB) ----
    const size_t NH = (size_t)NN * 64;
    float* A  = (float*)d_ws;                    // stem out / layer out
    float* xn = A + NH;                          // fp32 LN output (residual)

    char* extra = (char*)(xn + NH);
    unsigned short* xnb = (unsigned short*)extra; extra += NH * sizeof(short);
    unsigned short* rxb = (unsigned short*)extra; extra += NH * sizeof(short);
    unsigned short* cxb = (unsigned short*)extra; extra += NH * sizeof(short);
    float2* attsum = (float2*)extra;              extra += (size_t)NN * sizeof(float2);
    float* stats  = (float*)extra;                extra += 3 * 128 * sizeof(float);
    float* ac     = (float*)extra;                extra += 3 * 128 * sizeof(float);
    unsigned short* wbuf = (unsigned short*)extra; extra += 16384 * sizeof(short);
    int*   bsum   = (int*)extra;                  extra += 512 * sizeof(int);
    int*   bpre   = (int*)extra;                  extra += 512 * sizeof(int);
    int*   ptr    = (int*)extra;                  extra += (NB + 1) * sizeof(int);
    int*   counts = (int*)extra;                  extra += NB * sizeof(int);
    int*   cursor = (int*)extra;                  extra += NB * sizeof(int);
    int2*  edges  = (int2*)extra;                 extra += 2 * (size_t)EE * sizeof(int2);

    hipMemsetAsync(stats, 0, 3 * 128 * sizeof(float), stream);
    hipMemsetAsync(counts, 0, NB * sizeof(int), stream);

    // ---- CSR build (used by both layers) ----
    hist_kernel<<<2048, 256, 0, stream>>>(rowsrc, colsrc, counts);
    scan1_kernel<<<512, 256, 0, stream>>>(counts, bsum);
    scan2_kernel<<<1, 512, 0, stream>>>(bsum, bpre, ptr);
    scan3_kernel<<<512, 256, 0, stream>>>(counts, bpre, ptr, cursor);
    fill_win<<<2048, 256, 0, stream>>>(rowsrc, rowdst, row_att,
                                       colsrc, coldst, col_att,
                                       cursor, edges);
    w_convert<<<64, 256, 0, stream>>>(Wrv, Wcv, wbuf);

    // ---- stem ----
    stem_gemm<<<NN / 64, 256, 0, stream>>>(x, prelin_W, prelin_b, A);
    stats_kernel<<<1024, 256, 0, stream>>>(A, stats);
    finalize_bn<<<1, 64, 0, stream>>>(stats, bn0_g, bn0_b, ac);

    // ---- layer 0 ----
    ln_kernel<0><<<4096, 256, 0, stream>>>(A, ac, ln_g, ln_b, xn, xnb);
    gather_kernel<<<8192, 256, 0, stream>>>(xnb, ptr, edges, rxb, cxb, attsum);
    gemv_mfma<<<1024, 256, 0, stream>>>(rxb, cxb, xn, attsum, wbuf,
                                        brv, bcv, A, stats + 128);
    finalize_bn<<<1, 64, 0, stream>>>(stats + 128, bn_g, bn_b, ac + 128);

    // ---- layer 1 ----
    ln_kernel<1><<<4096, 256, 0, stream>>>(A, ac + 128, ln_g + 64, ln_b + 64, xn, xnb);
    gather_kernel<<<8192, 256, 0, stream>>>(xnb, ptr, edges, rxb, cxb, attsum);
    gemv_mfma<<<1024, 256, 0, stream>>>(rxb, cxb, xn, attsum, wbuf + 8192,
                                        brv + 64, bcv + 64, A, stats + 256);
    finalize_bn<<<1, 64, 0, stream>>>(stats + 256, bn_g + 64, bn_b + 64, ac + 256);

    // ---- output head ----
    out_kernel<<<2048, 256, 0, stream>>>(A, ac + 256, sm_W, sm_b, out);
}